// Round 1
// baseline (698.936 us; speedup 1.0000x reference)
//
#include <hip/hip_runtime.h>

#define Bsz 4
#define Tn 2048
#define Cn 1024
#define Hn 16
#define Dn 64
#define Mn (Bsz * Tn)      // 8192
#define NQKV (3 * Cn)      // 3072
#define BH (Bsz * Hn)      // 64

typedef short bf16x8_t __attribute__((ext_vector_type(8)));
typedef float f32x4 __attribute__((ext_vector_type(4)));

static __device__ __forceinline__ unsigned short f2bf(float f) {
    union { float f; unsigned int u; } v; v.f = f;
    unsigned int r = v.u + 0x7FFFu + ((v.u >> 16) & 1u);  // RNE
    return (unsigned short)(r >> 16);
}

static __device__ __forceinline__ bf16x8_t ld_frag_g(const unsigned short* p) {
    bf16x8_t r;
    *reinterpret_cast<float4*>(&r) = *reinterpret_cast<const float4*>(p);
    return r;
}

static __device__ __forceinline__ bf16x8_t ld_frag_lds(const unsigned short* p) {
    bf16x8_t r;
    reinterpret_cast<uint2*>(&r)[0] = reinterpret_cast<const uint2*>(p)[0];
    reinterpret_cast<uint2*>(&r)[1] = reinterpret_cast<const uint2*>(p)[1];
    return r;
}

// ---------------- cast f32 -> bf16 (vectorized) ----------------
__global__ void cast_f32_bf16(const float* __restrict__ src,
                              unsigned short* __restrict__ dst, int n4) {
    int i = blockIdx.x * blockDim.x + threadIdx.x;
    if (i < n4) {
        float4 v = reinterpret_cast<const float4*>(src)[i];
        ushort4 o;
        o.x = f2bf(v.x); o.y = f2bf(v.y); o.z = f2bf(v.z); o.w = f2bf(v.w);
        reinterpret_cast<ushort4*>(dst)[i] = o;
    }
}

// ---------------- cast + transpose: dst[c*R + r] = bf16(src[r*Cc + c]) ----------------
__global__ void transpose_cast(const float* __restrict__ src,
                               unsigned short* __restrict__ dst, int R, int Cc) {
    __shared__ float tile[32][33];
    int c0 = blockIdx.x * 32, r0 = blockIdx.y * 32;
    int tx = threadIdx.x & 31, ty = threadIdx.x >> 5;  // 256 threads: ty 0..7
#pragma unroll
    for (int i = 0; i < 4; i++)
        tile[ty + i * 8][tx] = src[(long)(r0 + ty + i * 8) * Cc + c0 + tx];
    __syncthreads();
#pragma unroll
    for (int i = 0; i < 4; i++)
        dst[(long)(c0 + ty + i * 8) * R + r0 + tx] = f2bf(tile[tx][ty + i * 8]);
}

// ---------------- GEMM: C[M,N] = A[M,K] @ Bt[N,K]^T + bias ----------------
// MODE 0: write fp32 to outF.   MODE 1: qkv scatter -> Qb/Kb (bh,t,d), Vt (bh,d,t), bf16.
template <int MODE>
__global__ __launch_bounds__(256) void gemm64(const unsigned short* __restrict__ A,
                                              const unsigned short* __restrict__ Bt,
                                              const float* __restrict__ bias,
                                              float* __restrict__ outF,
                                              unsigned short* __restrict__ Qb,
                                              unsigned short* __restrict__ Kb,
                                              unsigned short* __restrict__ Vt,
                                              int M, int N, int Kd) {
    __shared__ unsigned short As[64][40];
    __shared__ unsigned short Bs[64][40];
    int n0 = blockIdx.x * 64, m0 = blockIdx.y * 64;
    int tid = threadIdx.x;
    int lane = tid & 63, w = tid >> 6;
    int wm = w >> 1, wn = w & 1;
    int quad = lane >> 4, l15 = lane & 15;
    int srow = tid >> 2, scg = (tid & 3) * 8;

    f32x4 acc[2][2] = {};
    const unsigned short* Ag = A + (long)(m0 + srow) * Kd + scg;
    const unsigned short* Bg = Bt + (long)(n0 + srow) * Kd + scg;

    float4 av = *reinterpret_cast<const float4*>(Ag);
    float4 bv = *reinterpret_cast<const float4*>(Bg);
    for (int kb = 0; kb < Kd; kb += 32) {
        union { float4 f; uint2 u[2]; } ua, ub;
        ua.f = av; ub.f = bv;
        reinterpret_cast<uint2*>(&As[srow][scg])[0] = ua.u[0];
        reinterpret_cast<uint2*>(&As[srow][scg])[1] = ua.u[1];
        reinterpret_cast<uint2*>(&Bs[srow][scg])[0] = ub.u[0];
        reinterpret_cast<uint2*>(&Bs[srow][scg])[1] = ub.u[1];
        __syncthreads();
        if (kb + 32 < Kd) {  // prefetch next tile while MFMAs run
            av = *reinterpret_cast<const float4*>(Ag + kb + 32);
            bv = *reinterpret_cast<const float4*>(Bg + kb + 32);
        }
        bf16x8_t af[2], bfr[2];
#pragma unroll
        for (int r = 0; r < 2; r++) af[r] = ld_frag_lds(&As[wm * 32 + r * 16 + l15][quad * 8]);
#pragma unroll
        for (int c = 0; c < 2; c++) bfr[c] = ld_frag_lds(&Bs[wn * 32 + c * 16 + l15][quad * 8]);
#pragma unroll
        for (int r = 0; r < 2; r++)
#pragma unroll
            for (int c = 0; c < 2; c++)
                acc[r][c] = __builtin_amdgcn_mfma_f32_16x16x32_bf16(af[r], bfr[c], acc[r][c], 0, 0, 0);
        __syncthreads();
    }

#pragma unroll
    for (int r = 0; r < 2; r++)
#pragma unroll
        for (int c = 0; c < 2; c++) {
            int col = n0 + wn * 32 + c * 16 + l15;
            float bval = bias[col];
#pragma unroll
            for (int rr = 0; rr < 4; rr++) {
                int row = m0 + wm * 32 + r * 16 + quad * 4 + rr;
                float val = acc[r][c][rr] + bval;
                if (MODE == 0) {
                    outF[(long)row * N + col] = val;
                } else {
                    int seg = col >> 10, within = col & 1023;
                    int h = within >> 6, d = within & 63;
                    int b = row >> 11, t = row & 2047;
                    int bh = b * Hn + h;
                    unsigned short bfv = f2bf(val);
                    if (seg == 0)      Qb[((long)bh * Tn + t) * Dn + d] = bfv;
                    else if (seg == 1) Kb[((long)bh * Tn + t) * Dn + d] = bfv;
                    else               Vt[((long)bh * Dn + d) * Tn + t] = bfv;
                }
            }
        }
}

// ---------------- Flash attention: 1 wave = 16 q rows, block = 64 q rows ----------------
__global__ __launch_bounds__(256) void attn_kernel(const unsigned short* __restrict__ Qb,
                                                   const unsigned short* __restrict__ Kb,
                                                   const unsigned short* __restrict__ Vt,
                                                   unsigned short* __restrict__ Yb) {
    __shared__ unsigned short Plds[4][16][40];
    int bh = blockIdx.y;
    int q0b = blockIdx.x * 64;
    int tid = threadIdx.x, w = tid >> 6, lane = tid & 63;
    int quad = lane >> 4, l15 = lane & 15;
    int qw = q0b + w * 16;

    const unsigned short* Qh = Qb + (long)bh * Tn * Dn;
    const unsigned short* Kh = Kb + (long)bh * Tn * Dn;
    const unsigned short* Vh = Vt + (long)bh * Dn * Tn;

    bf16x8_t qf[2];
    qf[0] = ld_frag_g(&Qh[(qw + l15) * Dn + quad * 8]);
    qf[1] = ld_frag_g(&Qh[(qw + l15) * Dn + 32 + quad * 8]);

    float m_run = -1e30f, l_run = 0.f;
    f32x4 Of[4] = {};
    int q_glob = qw + l15;
    int kend = q0b + 64;

    for (int kt0 = 0; kt0 < kend; kt0 += 32) {
        // S^T[32t x 16q] = K_tile @ Q^T  (A = K rows, B = Q rows)
        f32x4 st[2];
#pragma unroll
        for (int ti = 0; ti < 2; ti++) {
            bf16x8_t ka0 = ld_frag_g(&Kh[(kt0 + ti * 16 + l15) * Dn + quad * 8]);
            bf16x8_t ka1 = ld_frag_g(&Kh[(kt0 + ti * 16 + l15) * Dn + 32 + quad * 8]);
            f32x4 z = {};
            z = __builtin_amdgcn_mfma_f32_16x16x32_bf16(ka0, qf[0], z, 0, 0, 0);
            st[ti] = __builtin_amdgcn_mfma_f32_16x16x32_bf16(ka1, qf[1], z, 0, 0, 0);
        }
        float p[2][4];
        float lmax = -1e30f;
#pragma unroll
        for (int ti = 0; ti < 2; ti++)
#pragma unroll
            for (int rr = 0; rr < 4; rr++) {
                int t_glob = kt0 + ti * 16 + quad * 4 + rr;
                float v = st[ti][rr] * 0.125f;
                if (t_glob > q_glob) v = -1e30f;
                p[ti][rr] = v;
                lmax = fmaxf(lmax, v);
            }
        lmax = fmaxf(lmax, __shfl_xor(lmax, 16));
        lmax = fmaxf(lmax, __shfl_xor(lmax, 32));
        float m_new = fmaxf(m_run, lmax);
        float alpha = __expf(m_run - m_new);
        float lsum = 0.f;
#pragma unroll
        for (int ti = 0; ti < 2; ti++)
#pragma unroll
            for (int rr = 0; rr < 4; rr++) {
                float e = __expf(p[ti][rr] - m_new);
                p[ti][rr] = e;
                lsum += e;
            }
        lsum += __shfl_xor(lsum, 16);
        lsum += __shfl_xor(lsum, 32);
        l_run = l_run * alpha + lsum;
        m_run = m_new;
#pragma unroll
        for (int rr = 0; rr < 4; rr++) {
            float a_rr = __shfl(alpha, quad * 4 + rr);
#pragma unroll
            for (int dt = 0; dt < 4; dt++) Of[dt][rr] *= a_rr;
        }
        // P (C-layout) -> LDS [q][t] -> A-layout
#pragma unroll
        for (int ti = 0; ti < 2; ti++) {
            unsigned int pk0 = (unsigned int)f2bf(p[ti][0]) | ((unsigned int)f2bf(p[ti][1]) << 16);
            unsigned int pk1 = (unsigned int)f2bf(p[ti][2]) | ((unsigned int)f2bf(p[ti][3]) << 16);
            *reinterpret_cast<unsigned int*>(&Plds[w][l15][ti * 16 + quad * 4]) = pk0;
            *reinterpret_cast<unsigned int*>(&Plds[w][l15][ti * 16 + quad * 4 + 2]) = pk1;
        }
        __syncthreads();
        bf16x8_t pa = ld_frag_lds(&Plds[w][l15][quad * 8]);
#pragma unroll
        for (int dt = 0; dt < 4; dt++) {
            bf16x8_t vb = ld_frag_g(&Vh[(dt * 16 + l15) * Tn + kt0 + quad * 8]);
            Of[dt] = __builtin_amdgcn_mfma_f32_16x16x32_bf16(pa, vb, Of[dt], 0, 0, 0);
        }
        __syncthreads();
    }

    int b = bh >> 4, h = bh & 15;
#pragma unroll
    for (int rr = 0; rr < 4; rr++) {
        float linv = 1.f / __shfl(l_run, quad * 4 + rr);
        int t = qw + quad * 4 + rr;
        long rowbase = ((long)(b * Tn + t)) * Cn + h * Dn;
#pragma unroll
        for (int dt = 0; dt < 4; dt++)
            Yb[rowbase + dt * 16 + l15] = f2bf(Of[dt][rr] * linv);
    }
}

extern "C" void kernel_launch(void* const* d_in, const int* in_sizes, int n_in,
                              void* d_out, int out_size, void* d_ws, size_t ws_size,
                              hipStream_t stream) {
    const float* x      = (const float*)d_in[0];
    const float* W_attn = (const float*)d_in[1];
    const float* b_attn = (const float*)d_in[2];
    const float* W_proj = (const float*)d_in[3];
    const float* b_proj = (const float*)d_in[4];
    float* out = (float*)d_out;

    unsigned short* xb      = (unsigned short*)d_ws;                 // [8192,1024]
    unsigned short* Wqkv_t  = xb + (size_t)Mn * Cn;                  // [3072,1024]
    unsigned short* Wproj_t = Wqkv_t + (size_t)NQKV * Cn;            // [1024,1024]
    unsigned short* Qb      = Wproj_t + (size_t)Cn * Cn;             // [64,2048,64]
    unsigned short* Kb      = Qb + (size_t)BH * Tn * Dn;
    unsigned short* Vt      = Kb + (size_t)BH * Tn * Dn;             // [64,64,2048]
    unsigned short* Yb      = Vt + (size_t)BH * Tn * Dn;             // [8192,1024]

    cast_f32_bf16<<<(Mn * Cn / 4 + 255) / 256, 256, 0, stream>>>(x, xb, Mn * Cn / 4);
    transpose_cast<<<dim3(NQKV / 32, Cn / 32), 256, 0, stream>>>(W_attn, Wqkv_t, Cn, NQKV);
    transpose_cast<<<dim3(Cn / 32, Cn / 32), 256, 0, stream>>>(W_proj, Wproj_t, Cn, Cn);

    gemm64<1><<<dim3(NQKV / 64, Mn / 64), 256, 0, stream>>>(
        xb, Wqkv_t, b_attn, nullptr, Qb, Kb, Vt, Mn, NQKV, Cn);

    attn_kernel<<<dim3(Tn / 64, BH), 256, 0, stream>>>(Qb, Kb, Vt, Yb);

    gemm64<0><<<dim3(Cn / 64, Mn / 64), 256, 0, stream>>>(
        Yb, Wproj_t, b_proj, out, nullptr, nullptr, nullptr, Mn, Cn, Cn);
}

// Round 2
// 482.917 us; speedup vs baseline: 1.4473x; 1.4473x over previous
//
#include <hip/hip_runtime.h>

#define Bsz 4
#define Tn 2048
#define Cn 1024
#define Hn 16
#define Dn 64
#define Mn (Bsz * Tn)      // 8192
#define NQKV (3 * Cn)      // 3072
#define BH (Bsz * Hn)      // 64

typedef short bf16x8_t __attribute__((ext_vector_type(8)));
typedef float f32x4 __attribute__((ext_vector_type(4)));

static __device__ __forceinline__ unsigned short f2bf(float f) {
    union { float f; unsigned int u; } v; v.f = f;
    unsigned int r = v.u + 0x7FFFu + ((v.u >> 16) & 1u);  // RNE
    return (unsigned short)(r >> 16);
}

static __device__ __forceinline__ unsigned int fbits(float f) {
    union { float f; unsigned int u; } v; v.f = f; return v.u;
}

static __device__ __forceinline__ bf16x8_t ld_frag_g(const unsigned short* p) {
    bf16x8_t r;
    *reinterpret_cast<float4*>(&r) = *reinterpret_cast<const float4*>(p);
    return r;
}

static __device__ __forceinline__ bf16x8_t ld_frag_lds(const unsigned short* p) {
    bf16x8_t r;
    *reinterpret_cast<float4*>(&r) = *reinterpret_cast<const float4*>(p);
    return r;
}

// async global->LDS, 16B per lane; LDS dest = wave-uniform base + lane*16
#define ASYNC_COPY16(gp, lp)                                                         \
    __builtin_amdgcn_global_load_lds((__attribute__((address_space(1))) void*)(gp),  \
                                     (__attribute__((address_space(3))) void*)(lp),  \
                                     16, 0, 0)

// ---------------- cast f32 -> bf16 (vectorized) ----------------
__global__ void cast_f32_bf16(const float* __restrict__ src,
                              unsigned short* __restrict__ dst, int n4) {
    int i = blockIdx.x * blockDim.x + threadIdx.x;
    if (i < n4) {
        float4 v = reinterpret_cast<const float4*>(src)[i];
        ushort4 o;
        o.x = f2bf(v.x); o.y = f2bf(v.y); o.z = f2bf(v.z); o.w = f2bf(v.w);
        reinterpret_cast<ushort4*>(dst)[i] = o;
    }
}

// ---------------- cast + transpose: dst[c*R + r] = bf16(src[r*Cc + c]) ----------------
__global__ void transpose_cast(const float* __restrict__ src,
                               unsigned short* __restrict__ dst, int R, int Cc) {
    __shared__ float tile[32][33];
    int c0 = blockIdx.x * 32, r0 = blockIdx.y * 32;
    int tx = threadIdx.x & 31, ty = threadIdx.x >> 5;  // 256 threads: ty 0..7
#pragma unroll
    for (int i = 0; i < 4; i++)
        tile[ty + i * 8][tx] = src[(long)(r0 + ty + i * 8) * Cc + c0 + tx];
    __syncthreads();
#pragma unroll
    for (int i = 0; i < 4; i++)
        dst[(long)(c0 + ty + i * 8) * R + r0 + tx] = f2bf(tile[tx][ty + i * 8]);
}

// ---------------- GEMM 128x128 (m97 recipe): C[M,N] = A[M,K] @ Bt[N,K]^T + bias ----------------
// MODE 0: write fp32 to outF.  MODE 1: qkv scatter -> Qb (pre-scaled 1/8) / Kb (bh,t,d), Vt (bh,d,t).
template <int MODE>
__global__ __launch_bounds__(256) void gemm128(const unsigned short* __restrict__ A,
                                               const unsigned short* __restrict__ Bt,
                                               const float* __restrict__ bias,
                                               float* __restrict__ outF,
                                               unsigned short* __restrict__ Qb,
                                               unsigned short* __restrict__ Kb,
                                               unsigned short* __restrict__ Vt,
                                               int M, int N, int Kd) {
    __shared__ __align__(16) unsigned short As[128 * 32];
    __shared__ __align__(16) unsigned short Bs[128 * 32];
    int n0 = blockIdx.x * 128, m0 = blockIdx.y * 128;
    int tid = threadIdx.x;
    int lane = tid & 63, w = tid >> 6;
    int wm = w >> 1, wn = w & 1;
    int quad = lane >> 4, l15 = lane & 15;
    int r = lane >> 2, c = lane & 3;  // staging: lane -> (row r, 8-elem chunk c)

    // each wave stages 2 x 16-row slabs of A and of B (1024B per instruction)
    const unsigned short* AgBase = A + (long)(m0 + w * 32 + r) * Kd + c * 8;
    const unsigned short* BgBase = Bt + (long)(n0 + w * 32 + r) * Kd + c * 8;
    unsigned short* ldsA = As + (w * 32) * 32;
    unsigned short* ldsB = Bs + (w * 32) * 32;

    f32x4 acc[4][4] = {};

    for (int kb = 0; kb < Kd; kb += 32) {
        ASYNC_COPY16(AgBase + kb, ldsA);
        ASYNC_COPY16(AgBase + 16 * Kd + kb, ldsA + 512);
        ASYNC_COPY16(BgBase + kb, ldsB);
        ASYNC_COPY16(BgBase + 16 * Kd + kb, ldsB + 512);
        __syncthreads();  // drains vmcnt -> staged tile visible
        bf16x8_t af[4], bfr[4];
#pragma unroll
        for (int i = 0; i < 4; i++)
            af[i] = ld_frag_lds(&As[(wm * 64 + i * 16 + l15) * 32 + quad * 8]);
#pragma unroll
        for (int j = 0; j < 4; j++)
            bfr[j] = ld_frag_lds(&Bs[(wn * 64 + j * 16 + l15) * 32 + quad * 8]);
#pragma unroll
        for (int i = 0; i < 4; i++)
#pragma unroll
            for (int j = 0; j < 4; j++)
                acc[i][j] = __builtin_amdgcn_mfma_f32_16x16x32_bf16(af[i], bfr[j], acc[i][j], 0, 0, 0);
        __syncthreads();  // all reads done before next stage overwrites
    }

#pragma unroll
    for (int i = 0; i < 4; i++)
#pragma unroll
        for (int j = 0; j < 4; j++) {
            int col = n0 + wn * 64 + j * 16 + l15;
            float bval = bias[col];
#pragma unroll
            for (int rr = 0; rr < 4; rr++) {
                int row = m0 + wm * 64 + i * 16 + quad * 4 + rr;
                float val = acc[i][j][rr] + bval;
                if (MODE == 0) {
                    outF[(long)row * N + col] = val;
                } else {
                    int seg = col >> 10, within = col & 1023;
                    int h = within >> 6, d = within & 63;
                    int b = row >> 11, t = row & 2047;
                    int bh = b * Hn + h;
                    if (seg == 0) {
                        Qb[((long)bh * Tn + t) * Dn + d] = f2bf(val * 0.125f);  // fold 1/sqrt(D)
                    } else if (seg == 1) {
                        Kb[((long)bh * Tn + t) * Dn + d] = f2bf(val);
                    } else {
                        Vt[((long)bh * Dn + d) * Tn + t] = f2bf(val);
                    }
                }
            }
        }
}

// ---------------- Flash attention ----------------
// Block = 4 waves; wave w handles 16 q rows. Each block processes TWO 64-row q-stripes
// {qi, 31-qi} sequentially -> every block does exactly 33 key-tiles (perfect balance).
// No __syncthreads anywhere: P round-trip LDS patch is per-wave private.
__global__ __launch_bounds__(256) void attn_kernel(const unsigned short* __restrict__ Qb,
                                                   const unsigned short* __restrict__ Kb,
                                                   const unsigned short* __restrict__ Vt,
                                                   unsigned short* __restrict__ Yb) {
    __shared__ __align__(16) unsigned short Plds[4][16][72];
    int tid = threadIdx.x, w = tid >> 6, lane = tid & 63;
    int quad = lane >> 4, l15 = lane & 15;
    int bh = blockIdx.y;
    int b = bh >> 4, h = bh & 15;

    const unsigned short* Qh = Qb + (long)bh * Tn * Dn;
    const unsigned short* Kh = Kb + (long)bh * Tn * Dn;
    const unsigned short* Vh = Vt + (long)bh * Dn * Tn;
    unsigned short* Pw = &Plds[w][0][0];

#pragma unroll 1
    for (int s = 0; s < 2; s++) {
        int qi = s ? (31 - (int)blockIdx.x) : (int)blockIdx.x;
        int q0b = qi * 64;
        int qw = q0b + w * 16;
        int q_glob = qw + l15;

        bf16x8_t qf0 = ld_frag_g(&Qh[(qw + l15) * Dn + quad * 8]);
        bf16x8_t qf1 = ld_frag_g(&Qh[(qw + l15) * Dn + 32 + quad * 8]);

        float m_run = -1e30f, l_run = 0.f;
        f32x4 Of[4] = {};

#pragma unroll 1
        for (int kt0 = 0; kt0 <= q0b; kt0 += 64) {
            // S^T[64k x 16q] = K_tile @ Q^T   (Q pre-scaled by 1/8 in QKV epilogue)
            f32x4 st[4];
#pragma unroll
            for (int ti = 0; ti < 4; ti++) {
                bf16x8_t ka0 = ld_frag_g(&Kh[(kt0 + ti * 16 + l15) * Dn + quad * 8]);
                bf16x8_t ka1 = ld_frag_g(&Kh[(kt0 + ti * 16 + l15) * Dn + 32 + quad * 8]);
                f32x4 z = {};
                z = __builtin_amdgcn_mfma_f32_16x16x32_bf16(ka0, qf0, z, 0, 0, 0);
                st[ti] = __builtin_amdgcn_mfma_f32_16x16x32_bf16(ka1, qf1, z, 0, 0, 0);
            }
            if (kt0 == q0b) {  // diagonal tile: causal mask (wave-uniform branch)
#pragma unroll
                for (int ti = 0; ti < 4; ti++)
#pragma unroll
                    for (int rr = 0; rr < 4; rr++)
                        if (kt0 + ti * 16 + quad * 4 + rr > q_glob) st[ti][rr] = -1e30f;
            }
            float lmax = st[0][0];
#pragma unroll
            for (int ti = 0; ti < 4; ti++)
#pragma unroll
                for (int rr = 0; rr < 4; rr++) lmax = fmaxf(lmax, st[ti][rr]);
            lmax = fmaxf(lmax, __shfl_xor(lmax, 16));
            lmax = fmaxf(lmax, __shfl_xor(lmax, 32));
            float m_new = fmaxf(m_run, lmax);
            float alpha = __expf(m_run - m_new);
            float lsum = 0.f;
#pragma unroll
            for (int ti = 0; ti < 4; ti++)
#pragma unroll
                for (int rr = 0; rr < 4; rr++) {
                    float e = __expf(st[ti][rr] - m_new);
                    st[ti][rr] = e;
                    lsum += e;
                }
            lsum += __shfl_xor(lsum, 16);
            lsum += __shfl_xor(lsum, 32);
            l_run = l_run * alpha + lsum;
            m_run = m_new;
#pragma unroll
            for (int rr = 0; rr < 4; rr++) {
                float a_rr = __shfl(alpha, quad * 4 + rr);
#pragma unroll
                for (int dt = 0; dt < 4; dt++) Of[dt][rr] *= a_rr;
            }
            // pack P -> per-wave LDS patch (half-up rounding via v_perm)
#pragma unroll
            for (int ti = 0; ti < 4; ti++) {
                unsigned u0 = fbits(st[ti][0]) + 0x8000u;
                unsigned u1 = fbits(st[ti][1]) + 0x8000u;
                unsigned u2 = fbits(st[ti][2]) + 0x8000u;
                unsigned u3 = fbits(st[ti][3]) + 0x8000u;
                uint2 pk;
                pk.x = __builtin_amdgcn_perm(u1, u0, 0x07060302);
                pk.y = __builtin_amdgcn_perm(u3, u2, 0x07060302);
                *reinterpret_cast<uint2*>(&Pw[l15 * 72 + ti * 16 + quad * 4]) = pk;
            }
            // PV: O[16q x 64d] += P[16q x 64k] @ V[64k x 64d]
#pragma unroll
            for (int kc = 0; kc < 2; kc++) {
                bf16x8_t pa = ld_frag_lds(&Pw[l15 * 72 + kc * 32 + quad * 8]);
#pragma unroll
                for (int dt = 0; dt < 4; dt++) {
                    bf16x8_t vb = ld_frag_g(&Vh[(dt * 16 + l15) * Tn + kt0 + kc * 32 + quad * 8]);
                    Of[dt] = __builtin_amdgcn_mfma_f32_16x16x32_bf16(pa, vb, Of[dt], 0, 0, 0);
                }
            }
        }

#pragma unroll
        for (int rr = 0; rr < 4; rr++) {
            float linv = 1.f / __shfl(l_run, quad * 4 + rr);
            int t = qw + quad * 4 + rr;
            long rowbase = ((long)(b * Tn + t)) * Cn + h * Dn;
#pragma unroll
            for (int dt = 0; dt < 4; dt++)
                Yb[rowbase + dt * 16 + l15] = f2bf(Of[dt][rr] * linv);
        }
    }
}

extern "C" void kernel_launch(void* const* d_in, const int* in_sizes, int n_in,
                              void* d_out, int out_size, void* d_ws, size_t ws_size,
                              hipStream_t stream) {
    const float* x      = (const float*)d_in[0];
    const float* W_attn = (const float*)d_in[1];
    const float* b_attn = (const float*)d_in[2];
    const float* W_proj = (const float*)d_in[3];
    const float* b_proj = (const float*)d_in[4];
    float* out = (float*)d_out;

    unsigned short* xb      = (unsigned short*)d_ws;                 // [8192,1024]
    unsigned short* Wqkv_t  = xb + (size_t)Mn * Cn;                  // [3072,1024]
    unsigned short* Wproj_t = Wqkv_t + (size_t)NQKV * Cn;            // [1024,1024]
    unsigned short* Qb      = Wproj_t + (size_t)Cn * Cn;             // [64,2048,64]
    unsigned short* Kb      = Qb + (size_t)BH * Tn * Dn;
    unsigned short* Vt      = Kb + (size_t)BH * Tn * Dn;             // [64,64,2048]
    unsigned short* Yb      = Vt + (size_t)BH * Tn * Dn;             // [8192,1024]

    cast_f32_bf16<<<(Mn * Cn / 4 + 255) / 256, 256, 0, stream>>>(x, xb, Mn * Cn / 4);
    transpose_cast<<<dim3(NQKV / 32, Cn / 32), 256, 0, stream>>>(W_attn, Wqkv_t, Cn, NQKV);
    transpose_cast<<<dim3(Cn / 32, Cn / 32), 256, 0, stream>>>(W_proj, Wproj_t, Cn, Cn);

    gemm128<1><<<dim3(NQKV / 128, Mn / 128), 256, 0, stream>>>(
        xb, Wqkv_t, b_attn, nullptr, Qb, Kb, Vt, Mn, NQKV, Cn);

    attn_kernel<<<dim3(16, BH), 256, 0, stream>>>(Qb, Kb, Vt, Yb);

    gemm128<0><<<dim3(Cn / 128, Mn / 128), 256, 0, stream>>>(
        Yb, Wproj_t, b_proj, out, nullptr, nullptr, nullptr, Mn, Cn, Cn);
}

// Round 4
// 308.003 us; speedup vs baseline: 2.2692x; 1.5679x over previous
//
#include <hip/hip_runtime.h>

#define Bsz 4
#define Tn 2048
#define Cn 1024
#define Hn 16
#define Dn 64
#define Mn (Bsz * Tn)      // 8192
#define NQKV (3 * Cn)      // 3072
#define BH (Bsz * Hn)      // 64

typedef short bf16x8_t __attribute__((ext_vector_type(8)));
typedef float f32x4 __attribute__((ext_vector_type(4)));

static __device__ __forceinline__ float exp2_fast(float x) {
    return __builtin_amdgcn_exp2f(x);  // v_exp_f32 (base-2)
}

static __device__ __forceinline__ unsigned short f2bf(float f) {
    union { float f; unsigned int u; } v; v.f = f;
    unsigned int r = v.u + 0x7FFFu + ((v.u >> 16) & 1u);  // RNE
    return (unsigned short)(r >> 16);
}

static __device__ __forceinline__ unsigned int fbits(float f) {
    union { float f; unsigned int u; } v; v.f = f; return v.u;
}

static __device__ __forceinline__ bf16x8_t ld_frag(const unsigned short* p) {
    bf16x8_t r;
    *reinterpret_cast<float4*>(&r) = *reinterpret_cast<const float4*>(p);
    return r;
}

// async global->LDS, 16B per lane; LDS dest = wave-uniform base + lane*16
#define ASYNC_COPY16(gp, lp)                                                         \
    __builtin_amdgcn_global_load_lds((__attribute__((address_space(1))) void*)(gp),  \
                                     (__attribute__((address_space(3))) void*)(lp),  \
                                     16, 0, 0)

// ---------------- cast f32 -> bf16 (vectorized) ----------------
__global__ void cast_f32_bf16(const float* __restrict__ src,
                              unsigned short* __restrict__ dst, int n4) {
    int i = blockIdx.x * blockDim.x + threadIdx.x;
    if (i < n4) {
        float4 v = reinterpret_cast<const float4*>(src)[i];
        ushort4 o;
        o.x = f2bf(v.x); o.y = f2bf(v.y); o.z = f2bf(v.z); o.w = f2bf(v.w);
        reinterpret_cast<ushort4*>(dst)[i] = o;
    }
}

// ---------------- cast + transpose: dst[c*R + r] = bf16(src[r*Cc + c]) ----------------
__global__ void transpose_cast(const float* __restrict__ src,
                               unsigned short* __restrict__ dst, int R, int Cc) {
    __shared__ float tile[32][33];
    int c0 = blockIdx.x * 32, r0 = blockIdx.y * 32;
    int tx = threadIdx.x & 31, ty = threadIdx.x >> 5;  // 256 threads: ty 0..7
#pragma unroll
    for (int i = 0; i < 4; i++)
        tile[ty + i * 8][tx] = src[(long)(r0 + ty + i * 8) * Cc + c0 + tx];
    __syncthreads();
#pragma unroll
    for (int i = 0; i < 4; i++)
        dst[(long)(c0 + ty + i * 8) * R + r0 + tx] = f2bf(tile[tx][ty + i * 8]);
}

// ---------------- GEMM 128x128 (m97 recipe): C[M,N] = A[M,K] @ Bt[N,K]^T + bias ----------------
// MODE 0: write fp32 to outF.  MODE 1: qkv scatter -> Qb (pre-scaled 0.125*log2e) / Kb (bh,t,d), Vt (bh,d,t).
template <int MODE>
__global__ __launch_bounds__(256) void gemm128(const unsigned short* __restrict__ A,
                                               const unsigned short* __restrict__ Bt,
                                               const float* __restrict__ bias,
                                               float* __restrict__ outF,
                                               unsigned short* __restrict__ Qb,
                                               unsigned short* __restrict__ Kb,
                                               unsigned short* __restrict__ Vt,
                                               int M, int N, int Kd) {
    __shared__ __align__(16) unsigned short As[128 * 32];
    __shared__ __align__(16) unsigned short Bs[128 * 32];
    int n0 = blockIdx.x * 128, m0 = blockIdx.y * 128;
    int tid = threadIdx.x;
    int lane = tid & 63, w = tid >> 6;
    int wm = w >> 1, wn = w & 1;
    int quad = lane >> 4, l15 = lane & 15;
    int r = lane >> 2, c = lane & 3;  // staging: lane -> (row r, 8-elem chunk c)

    const unsigned short* AgBase = A + (long)(m0 + w * 32 + r) * Kd + c * 8;
    const unsigned short* BgBase = Bt + (long)(n0 + w * 32 + r) * Kd + c * 8;
    unsigned short* ldsA = As + (w * 32) * 32;
    unsigned short* ldsB = Bs + (w * 32) * 32;

    f32x4 acc[4][4] = {};

    for (int kb = 0; kb < Kd; kb += 32) {
        ASYNC_COPY16(AgBase + kb, ldsA);
        ASYNC_COPY16(AgBase + 16 * Kd + kb, ldsA + 512);
        ASYNC_COPY16(BgBase + kb, ldsB);
        ASYNC_COPY16(BgBase + 16 * Kd + kb, ldsB + 512);
        __syncthreads();
        bf16x8_t af[4], bfr[4];
#pragma unroll
        for (int i = 0; i < 4; i++)
            af[i] = ld_frag(&As[(wm * 64 + i * 16 + l15) * 32 + quad * 8]);
#pragma unroll
        for (int j = 0; j < 4; j++)
            bfr[j] = ld_frag(&Bs[(wn * 64 + j * 16 + l15) * 32 + quad * 8]);
#pragma unroll
        for (int i = 0; i < 4; i++)
#pragma unroll
            for (int j = 0; j < 4; j++)
                acc[i][j] = __builtin_amdgcn_mfma_f32_16x16x32_bf16(af[i], bfr[j], acc[i][j], 0, 0, 0);
        __syncthreads();
    }

#pragma unroll
    for (int i = 0; i < 4; i++)
#pragma unroll
        for (int j = 0; j < 4; j++) {
            int col = n0 + wn * 64 + j * 16 + l15;
            float bval = bias[col];
#pragma unroll
            for (int rr = 0; rr < 4; rr++) {
                int row = m0 + wm * 64 + i * 16 + quad * 4 + rr;
                float val = acc[i][j][rr] + bval;
                if (MODE == 0) {
                    outF[(long)row * N + col] = val;
                } else {
                    int seg = col >> 10, within = col & 1023;
                    int h = within >> 6, d = within & 63;
                    int b = row >> 11, t = row & 2047;
                    int bh = b * Hn + h;
                    if (seg == 0) {
                        // fold 1/sqrt(D) AND log2(e) so softmax uses exp2 directly
                        Qb[((long)bh * Tn + t) * Dn + d] = f2bf(val * 0.18033688f);
                    } else if (seg == 1) {
                        Kb[((long)bh * Tn + t) * Dn + d] = f2bf(val);
                    } else {
                        Vt[((long)bh * Dn + d) * Tn + t] = f2bf(val);
                    }
                }
            }
        }
}

// ---------------- Flash attention v3 ----------------
// Block = 4 waves, covers a 128-row q-stripe (32 q rows/wave as 2 halves).
// Stripes paired {qi, 15-qi} -> uniform 34 key-tiles/block. K/V tiles staged
// cooperatively into padded LDS with register-prefetch pipeline (1 tile ahead).
__global__ __launch_bounds__(256) void attn_kernel(const unsigned short* __restrict__ Qb,
                                                   const unsigned short* __restrict__ Kb,
                                                   const unsigned short* __restrict__ Vt,
                                                   unsigned short* __restrict__ Yb) {
    __shared__ __align__(16) unsigned short Ks[64 * 72];
    __shared__ __align__(16) unsigned short Vs[64 * 72];
    __shared__ __align__(16) unsigned short Plds[4][2][16 * 72];
    int tid = threadIdx.x, w = tid >> 6, lane = tid & 63;
    int quad = lane >> 4, l15 = lane & 15;

    // XCD swizzle: all 8 stripe-blocks of one bh land on the same XCD (id%8 heuristic)
    int flat = blockIdx.y * 8 + blockIdx.x;
    int xcd = flat & 7, slot = flat >> 3;
    int bh = xcd * 8 + (slot >> 3);
    int qx = slot & 7;
    int b = bh >> 4, h = bh & 15;

    const unsigned short* Qh = Qb + (long)bh * Tn * Dn;
    const unsigned short* Kh = Kb + (long)bh * Tn * Dn;
    const unsigned short* Vh = Vt + (long)bh * Dn * Tn;

    int sr = tid >> 3;          // staging row 0..31
    int sc = (tid & 7) * 8;     // staging elem offset

#pragma unroll 1
    for (int s = 0; s < 2; s++) {
        int qi = s ? (15 - qx) : qx;
        int q0b = qi * 128;
        int nt = 2 * qi + 2;

        bf16x8_t qf[2][2];
#pragma unroll
        for (int h2 = 0; h2 < 2; h2++) {
            int qrow = q0b + h2 * 64 + w * 16 + l15;
            qf[h2][0] = ld_frag(&Qh[qrow * Dn + quad * 8]);
            qf[h2][1] = ld_frag(&Qh[qrow * Dn + 32 + quad * 8]);
        }

        float m_run[2] = {-1e30f, -1e30f}, l_run[2] = {0.f, 0.f};
        f32x4 Of[2][4] = {};

        // prefetch tile 0 into registers
        float4 kr0 = *reinterpret_cast<const float4*>(&Kh[sr * Dn + sc]);
        float4 kr1 = *reinterpret_cast<const float4*>(&Kh[(32 + sr) * Dn + sc]);
        float4 vr0 = *reinterpret_cast<const float4*>(&Vh[sr * Tn + sc]);
        float4 vr1 = *reinterpret_cast<const float4*>(&Vh[(32 + sr) * Tn + sc]);

#pragma unroll 1
        for (int t = 0; t < nt; t++) {
            int kt0 = t * 64;
            __syncthreads();  // everyone done reading previous LDS tile
            *reinterpret_cast<float4*>(&Ks[sr * 72 + sc]) = kr0;
            *reinterpret_cast<float4*>(&Ks[(32 + sr) * 72 + sc]) = kr1;
            *reinterpret_cast<float4*>(&Vs[sr * 72 + sc]) = vr0;
            *reinterpret_cast<float4*>(&Vs[(32 + sr) * 72 + sc]) = vr1;
            if (t + 1 < nt) {  // issue next tile's loads; latency hides behind compute(t)
                int kn = kt0 + 64;
                kr0 = *reinterpret_cast<const float4*>(&Kh[(kn + sr) * Dn + sc]);
                kr1 = *reinterpret_cast<const float4*>(&Kh[(kn + 32 + sr) * Dn + sc]);
                vr0 = *reinterpret_cast<const float4*>(&Vh[sr * Tn + kn + sc]);
                vr1 = *reinterpret_cast<const float4*>(&Vh[(32 + sr) * Tn + kn + sc]);
            }
            __syncthreads();  // staged tile visible

            bool act0 = (kt0 <= q0b);  // half 0 active? (block-uniform)

            // QK^T for both halves, sharing K fragments
            f32x4 st[2][4];
#pragma unroll
            for (int ti = 0; ti < 4; ti++) {
                bf16x8_t ka0 = ld_frag(&Ks[(ti * 16 + l15) * 72 + quad * 8]);
                bf16x8_t ka1 = ld_frag(&Ks[(ti * 16 + l15) * 72 + 32 + quad * 8]);
                if (act0) {
                    f32x4 z = {};
                    z = __builtin_amdgcn_mfma_f32_16x16x32_bf16(ka0, qf[0][0], z, 0, 0, 0);
                    st[0][ti] = __builtin_amdgcn_mfma_f32_16x16x32_bf16(ka1, qf[0][1], z, 0, 0, 0);
                }
                f32x4 z1 = {};
                z1 = __builtin_amdgcn_mfma_f32_16x16x32_bf16(ka0, qf[1][0], z1, 0, 0, 0);
                st[1][ti] = __builtin_amdgcn_mfma_f32_16x16x32_bf16(ka1, qf[1][1], z1, 0, 0, 0);
            }

            // softmax + P-pack per half
            bf16x8_t pa[2][2];
#pragma unroll
            for (int h2 = 0; h2 < 2; h2++) {
                int qbase = q0b + h2 * 64;
                if (h2 == 0 && !act0) continue;
                if (kt0 == qbase) {  // diagonal tile: causal mask
                    int q_glob = qbase + w * 16 + l15;
#pragma unroll
                    for (int ti = 0; ti < 4; ti++)
#pragma unroll
                        for (int rr = 0; rr < 4; rr++)
                            if (kt0 + ti * 16 + quad * 4 + rr > q_glob) st[h2][ti][rr] = -1e30f;
                }
                float lmax = st[h2][0][0];
#pragma unroll
                for (int ti = 0; ti < 4; ti++)
#pragma unroll
                    for (int rr = 0; rr < 4; rr++) lmax = fmaxf(lmax, st[h2][ti][rr]);
                lmax = fmaxf(lmax, __shfl_xor(lmax, 16));
                lmax = fmaxf(lmax, __shfl_xor(lmax, 32));
                float m_new = fmaxf(m_run[h2], lmax);
                float alpha = exp2_fast(m_run[h2] - m_new);
                float lsum = 0.f;
#pragma unroll
                for (int ti = 0; ti < 4; ti++)
#pragma unroll
                    for (int rr = 0; rr < 4; rr++) {
                        float e = exp2_fast(st[h2][ti][rr] - m_new);
                        st[h2][ti][rr] = e;
                        lsum += e;
                    }
                lsum += __shfl_xor(lsum, 16);
                lsum += __shfl_xor(lsum, 32);
                l_run[h2] = l_run[h2] * alpha + lsum;
                m_run[h2] = m_new;
#pragma unroll
                for (int rr = 0; rr < 4; rr++) {
                    float a_rr = __shfl(alpha, quad * 4 + rr);
#pragma unroll
                    for (int dt = 0; dt < 4; dt++) Of[h2][dt][rr] *= a_rr;
                }
                unsigned short* Pw = &Plds[w][h2][0];
#pragma unroll
                for (int ti = 0; ti < 4; ti++) {
                    unsigned u0 = fbits(st[h2][ti][0]) + 0x8000u;
                    unsigned u1 = fbits(st[h2][ti][1]) + 0x8000u;
                    unsigned u2 = fbits(st[h2][ti][2]) + 0x8000u;
                    unsigned u3 = fbits(st[h2][ti][3]) + 0x8000u;
                    uint2 pk;
                    pk.x = __builtin_amdgcn_perm(u1, u0, 0x07060302);
                    pk.y = __builtin_amdgcn_perm(u3, u2, 0x07060302);
                    *reinterpret_cast<uint2*>(&Pw[l15 * 72 + ti * 16 + quad * 4]) = pk;
                }
#pragma unroll
                for (int kc = 0; kc < 2; kc++)
                    pa[h2][kc] = ld_frag(&Pw[l15 * 72 + kc * 32 + quad * 8]);
            }

            // PV for both halves, sharing V fragments
#pragma unroll
            for (int kc = 0; kc < 2; kc++)
#pragma unroll
                for (int dt = 0; dt < 4; dt++) {
                    bf16x8_t vb = ld_frag(&Vs[(dt * 16 + l15) * 72 + kc * 32 + quad * 8]);
                    if (act0)
                        Of[0][dt] = __builtin_amdgcn_mfma_f32_16x16x32_bf16(pa[0][kc], vb, Of[0][dt], 0, 0, 0);
                    Of[1][dt] = __builtin_amdgcn_mfma_f32_16x16x32_bf16(pa[1][kc], vb, Of[1][dt], 0, 0, 0);
                }
        }

#pragma unroll
        for (int h2 = 0; h2 < 2; h2++) {
            int qw = q0b + h2 * 64 + w * 16;
#pragma unroll
            for (int rr = 0; rr < 4; rr++) {
                float linv = 1.f / __shfl(l_run[h2], quad * 4 + rr);
                int t = qw + quad * 4 + rr;
                long rowbase = ((long)(b * Tn + t)) * Cn + h * Dn;
#pragma unroll
                for (int dt = 0; dt < 4; dt++)
                    Yb[rowbase + dt * 16 + l15] = f2bf(Of[h2][dt][rr] * linv);
            }
        }
    }
}

extern "C" void kernel_launch(void* const* d_in, const int* in_sizes, int n_in,
                              void* d_out, int out_size, void* d_ws, size_t ws_size,
                              hipStream_t stream) {
    const float* x      = (const float*)d_in[0];
    const float* W_attn = (const float*)d_in[1];
    const float* b_attn = (const float*)d_in[2];
    const float* W_proj = (const float*)d_in[3];
    const float* b_proj = (const float*)d_in[4];
    float* out = (float*)d_out;

    unsigned short* xb      = (unsigned short*)d_ws;                 // [8192,1024]
    unsigned short* Wqkv_t  = xb + (size_t)Mn * Cn;                  // [3072,1024]
    unsigned short* Wproj_t = Wqkv_t + (size_t)NQKV * Cn;            // [1024,1024]
    unsigned short* Qb      = Wproj_t + (size_t)Cn * Cn;             // [64,2048,64]
    unsigned short* Kb      = Qb + (size_t)BH * Tn * Dn;
    unsigned short* Vt      = Kb + (size_t)BH * Tn * Dn;             // [64,64,2048]
    unsigned short* Yb      = Vt + (size_t)BH * Tn * Dn;             // [8192,1024]

    cast_f32_bf16<<<(Mn * Cn / 4 + 255) / 256, 256, 0, stream>>>(x, xb, Mn * Cn / 4);
    transpose_cast<<<dim3(NQKV / 32, Cn / 32), 256, 0, stream>>>(W_attn, Wqkv_t, Cn, NQKV);
    transpose_cast<<<dim3(Cn / 32, Cn / 32), 256, 0, stream>>>(W_proj, Wproj_t, Cn, Cn);

    gemm128<1><<<dim3(NQKV / 128, Mn / 128), 256, 0, stream>>>(
        xb, Wqkv_t, b_attn, nullptr, Qb, Kb, Vt, Mn, NQKV, Cn);

    attn_kernel<<<dim3(8, BH), 256, 0, stream>>>(Qb, Kb, Vt, Yb);

    gemm128<0><<<dim3(Cn / 128, Mn / 128), 256, 0, stream>>>(
        Yb, Wproj_t, b_proj, out, nullptr, nullptr, nullptr, Mn, Cn, Cn);
}